// Round 3
// baseline (83.873 us; speedup 1.0000x reference)
//
#include <hip/hip_runtime.h>
#include <math.h>

#define NEG_SLOPE 0.01f

// Kernel 1 (fused): per-node dot products + segment starts.
// One wave per node; lane = feature (F==64). Lane 0 additionally binary-searches
// sorted dst for this node's first edge index.
__global__ void prep(const float* __restrict__ h, const float* __restrict__ w,
                     const int* __restrict__ dst,
                     float* __restrict__ a_src, float* __restrict__ a_dst,
                     int* __restrict__ seg, int N, int E) {
    int wid  = (int)((blockIdx.x * blockDim.x + threadIdx.x) >> 6);
    int lane = threadIdx.x & 63;
    if (wid >= N) return;
    float hv = h[(long)wid * 64 + lane];
    float ps = hv * w[lane];
    float pd = hv * w[64 + lane];
    #pragma unroll
    for (int o = 32; o; o >>= 1) {
        ps += __shfl_xor(ps, o);
        pd += __shfl_xor(pd, o);
    }
    if (lane == 0) {
        a_src[wid] = ps;
        a_dst[wid] = pd;
        int lo = 0, hi = E;
        while (lo < hi) {
            int mid = (lo + hi) >> 1;
            if (dst[mid] < wid) lo = mid + 1; else hi = mid;
        }
        seg[wid] = lo;
        if (wid == 0) seg[N] = E;
    }
}

// Kernel 2: one wave per dst node.
// Softmax: lane l owns edge s+l (deg<=64 fast path), alpha kept in register.
// Accumulate: 16 lanes/edge x 4 edges/iter; lane (g=lane>>4, q=lane&15) loads
// float4 of features q*4..q*4+3 of edge j0+g. Cross-group shfl_xor reduce at end.
__global__ void gat_out(const float* __restrict__ h, const float* __restrict__ a_src,
                        const float* __restrict__ a_dst, const int* __restrict__ src,
                        const int* __restrict__ seg, float* __restrict__ out, int N) {
    int wid  = (int)((blockIdx.x * blockDim.x + threadIdx.x) >> 6);
    int lane = threadIdx.x & 63;
    if (wid >= N) return;
    int s    = seg[wid];
    int eend = seg[wid + 1];
    int deg  = eend - s;
    int q    = lane & 15, g = lane >> 4;
    if (deg <= 0) {
        if (lane < 16) {
            float4 z = {0.0f, 0.0f, 0.0f, 0.0f};
            *(float4*)(out + (long)wid * 64 + lane * 4) = z;
        }
        return;
    }
    float ad = a_dst[wid];

    if (deg <= 64) {
        bool v  = (lane < deg);
        int  sj = v ? src[s + lane] : 0;
        float e = a_src[sj] + ad;
        e = (e >= 0.0f) ? e : NEG_SLOPE * e;
        if (!v) e = -INFINITY;

        float m = e;
        #pragma unroll
        for (int o = 32; o; o >>= 1) m = fmaxf(m, __shfl_xor(m, o));

        float p = v ? __expf(e - m) : 0.0f;
        float dsum = p;
        #pragma unroll
        for (int o = 32; o; o >>= 1) dsum += __shfl_xor(dsum, o);
        p *= (1.0f / dsum);                       // alpha for this lane's edge (0 if invalid)

        float4 acc = {0.0f, 0.0f, 0.0f, 0.0f};
        const float* hq = h + q * 4;
        #pragma unroll 4
        for (int j0 = 0; j0 < deg; j0 += 4) {
            int   j   = j0 + g;                   // j<=63 always; alpha=0 past deg
            float aj  = __shfl(p, j);
            int   sjj = __shfl(sj, j);
            float4 hv = *(const float4*)(hq + (long)sjj * 64);
            acc.x = fmaf(aj, hv.x, acc.x);
            acc.y = fmaf(aj, hv.y, acc.y);
            acc.z = fmaf(aj, hv.z, acc.z);
            acc.w = fmaf(aj, hv.w, acc.w);
        }
        // sum the 4 edge-groups (lanes differing in bits 4,5)
        #pragma unroll
        for (int o = 32; o >= 16; o >>= 1) {
            acc.x += __shfl_xor(acc.x, o);
            acc.y += __shfl_xor(acc.y, o);
            acc.z += __shfl_xor(acc.z, o);
            acc.w += __shfl_xor(acc.w, o);
        }
        if (lane < 16) *(float4*)(out + (long)wid * 64 + lane * 4) = acc;
    } else {
        // Rare fallback (deg>64): 3-pass chunked, serial accumulation.
        float m = -INFINITY;
        for (int i = s + lane; i < eend; i += 64) {
            float e = a_src[src[i]] + ad;
            e = (e >= 0.0f) ? e : NEG_SLOPE * e;
            m = fmaxf(m, e);
        }
        #pragma unroll
        for (int o = 32; o; o >>= 1) m = fmaxf(m, __shfl_xor(m, o));

        float dsum = 0.0f;
        for (int i = s + lane; i < eend; i += 64) {
            float e = a_src[src[i]] + ad;
            e = (e >= 0.0f) ? e : NEG_SLOPE * e;
            dsum += __expf(e - m);
        }
        #pragma unroll
        for (int o = 32; o; o >>= 1) dsum += __shfl_xor(dsum, o);
        float inv = 1.0f / dsum;

        float acc = 0.0f;
        for (int i = s; i < eend; ++i) {
            int   sj    = src[i];
            float e     = a_src[sj] + ad;
            e = (e >= 0.0f) ? e : NEG_SLOPE * e;
            float alpha = __expf(e - m) * inv;
            acc = fmaf(alpha, h[(long)sj * 64 + lane], acc);
        }
        out[(long)wid * 64 + lane] = acc;
    }
}

extern "C" void kernel_launch(void* const* d_in, const int* in_sizes, int n_in,
                              void* d_out, int out_size, void* d_ws, size_t ws_size,
                              hipStream_t stream) {
    const float* h   = (const float*)d_in[0];
    const float* w   = (const float*)d_in[1];
    const int*   src = (const int*)d_in[2];
    const int*   dst = (const int*)d_in[3];
    float*       out = (float*)d_out;

    const int F = in_sizes[1] / 2;       // 64
    const int N = in_sizes[0] / F;       // 50000
    const int E = in_sizes[2];           // 800000

    float* a_src = (float*)d_ws;
    float* a_dst = a_src + N;
    int*   seg   = (int*)(a_dst + N);    // N+1 ints

    prep<<<dim3((N + 3) / 4), dim3(256), 0, stream>>>(h, w, dst, a_src, a_dst, seg, N, E);
    gat_out<<<dim3((N + 3) / 4), dim3(256), 0, stream>>>(h, a_src, a_dst, src, seg, out, N);
}

// Round 4
// 45.678 us; speedup vs baseline: 1.8362x; 1.8362x over previous
//
#include <hip/hip_runtime.h>
#include <math.h>

#define NEG_SLOPE 0.01f

// Kernel 1: per-node dot products. 16 lanes per node (wave = 4 nodes).
// Lane q of group g loads float4 features [q*4..q*4+3] of node wid4+g.
__global__ void prep(const float* __restrict__ h, const float* __restrict__ w,
                     float* __restrict__ a_src, float* __restrict__ a_dst, int N) {
    int gid  = blockIdx.x * blockDim.x + threadIdx.x;
    int node = gid >> 4;           // 16 lanes per node
    int q    = gid & 15;
    if (node >= N) return;
    float4 hv = *(const float4*)(h + (long)node * 64 + q * 4);
    float4 ws = *(const float4*)(w + q * 4);
    float4 wd = *(const float4*)(w + 64 + q * 4);
    float ps = hv.x * ws.x + hv.y * ws.y + hv.z * ws.z + hv.w * ws.w;
    float pd = hv.x * wd.x + hv.y * wd.y + hv.z * wd.z + hv.w * wd.w;
    #pragma unroll
    for (int o = 8; o; o >>= 1) {
        ps += __shfl_xor(ps, o);
        pd += __shfl_xor(pd, o);
    }
    if (q == 0) { a_src[node] = ps; a_dst[node] = pd; }
}

// Kernel 2: edge-parallel segment boundaries over sorted dst.
// seg[n] = first edge index with dst[i] >= n; seg[N] = E.
// Edge i owns all n in (dst[i-1], dst[i]]; last edge also fills the tail.
__global__ void seg_edges(const int* __restrict__ dst, int* __restrict__ seg,
                          int N, int E) {
    int i = blockIdx.x * blockDim.x + threadIdx.x;
    if (i >= E) return;
    int d    = dst[i];
    int prev = (i == 0) ? -1 : dst[i - 1];
    for (int n = prev + 1; n <= d; ++n) seg[n] = i;
    if (i == E - 1) {
        for (int n = d + 1; n <= N; ++n) seg[n] = E;
    }
}

// Kernel 3: one wave per dst node.
// Softmax: lane l owns edge s+l (deg<=64 fast path), alpha kept in register.
// Accumulate: 16 lanes/edge x 4 edges/iter; lane (g=lane>>4, q=lane&15) loads
// float4 of features q*4..q*4+3 of edge j0+g. Cross-group shfl_xor reduce at end.
__global__ void gat_out(const float* __restrict__ h, const float* __restrict__ a_src,
                        const float* __restrict__ a_dst, const int* __restrict__ src,
                        const int* __restrict__ seg, float* __restrict__ out, int N) {
    int wid  = (int)((blockIdx.x * blockDim.x + threadIdx.x) >> 6);
    int lane = threadIdx.x & 63;
    if (wid >= N) return;
    int s    = seg[wid];
    int eend = seg[wid + 1];
    int deg  = eend - s;
    int q    = lane & 15, g = lane >> 4;
    if (deg <= 0) {
        if (lane < 16) {
            float4 z = {0.0f, 0.0f, 0.0f, 0.0f};
            *(float4*)(out + (long)wid * 64 + lane * 4) = z;
        }
        return;
    }
    float ad = a_dst[wid];

    if (deg <= 64) {
        bool v  = (lane < deg);
        int  sj = v ? src[s + lane] : 0;
        float e = a_src[sj] + ad;
        e = (e >= 0.0f) ? e : NEG_SLOPE * e;
        if (!v) e = -INFINITY;

        float m = e;
        #pragma unroll
        for (int o = 32; o; o >>= 1) m = fmaxf(m, __shfl_xor(m, o));

        float p = v ? __expf(e - m) : 0.0f;
        float dsum = p;
        #pragma unroll
        for (int o = 32; o; o >>= 1) dsum += __shfl_xor(dsum, o);
        p *= (1.0f / dsum);                       // alpha for this lane's edge (0 if invalid)

        float4 acc = {0.0f, 0.0f, 0.0f, 0.0f};
        const float* hq = h + q * 4;
        #pragma unroll 4
        for (int j0 = 0; j0 < deg; j0 += 4) {
            int   j   = j0 + g;                   // j<=63 always; alpha=0 past deg
            float aj  = __shfl(p, j);
            int   sjj = __shfl(sj, j);
            float4 hv = *(const float4*)(hq + (long)sjj * 64);
            acc.x = fmaf(aj, hv.x, acc.x);
            acc.y = fmaf(aj, hv.y, acc.y);
            acc.z = fmaf(aj, hv.z, acc.z);
            acc.w = fmaf(aj, hv.w, acc.w);
        }
        #pragma unroll
        for (int o = 32; o >= 16; o >>= 1) {
            acc.x += __shfl_xor(acc.x, o);
            acc.y += __shfl_xor(acc.y, o);
            acc.z += __shfl_xor(acc.z, o);
            acc.w += __shfl_xor(acc.w, o);
        }
        if (lane < 16) *(float4*)(out + (long)wid * 64 + lane * 4) = acc;
    } else {
        // Rare fallback (deg>64): 3-pass chunked, serial accumulation.
        float m = -INFINITY;
        for (int i = s + lane; i < eend; i += 64) {
            float e = a_src[src[i]] + ad;
            e = (e >= 0.0f) ? e : NEG_SLOPE * e;
            m = fmaxf(m, e);
        }
        #pragma unroll
        for (int o = 32; o; o >>= 1) m = fmaxf(m, __shfl_xor(m, o));

        float dsum = 0.0f;
        for (int i = s + lane; i < eend; i += 64) {
            float e = a_src[src[i]] + ad;
            e = (e >= 0.0f) ? e : NEG_SLOPE * e;
            dsum += __expf(e - m);
        }
        #pragma unroll
        for (int o = 32; o; o >>= 1) dsum += __shfl_xor(dsum, o);
        float inv = 1.0f / dsum;

        float acc = 0.0f;
        for (int i = s; i < eend; ++i) {
            int   sj    = src[i];
            float e     = a_src[sj] + ad;
            e = (e >= 0.0f) ? e : NEG_SLOPE * e;
            float alpha = __expf(e - m) * inv;
            acc = fmaf(alpha, h[(long)sj * 64 + lane], acc);
        }
        out[(long)wid * 64 + lane] = acc;
    }
}

extern "C" void kernel_launch(void* const* d_in, const int* in_sizes, int n_in,
                              void* d_out, int out_size, void* d_ws, size_t ws_size,
                              hipStream_t stream) {
    const float* h   = (const float*)d_in[0];
    const float* w   = (const float*)d_in[1];
    const int*   src = (const int*)d_in[2];
    const int*   dst = (const int*)d_in[3];
    float*       out = (float*)d_out;

    const int F = in_sizes[1] / 2;       // 64
    const int N = in_sizes[0] / F;       // 50000
    const int E = in_sizes[2];           // 800000

    float* a_src = (float*)d_ws;
    float* a_dst = a_src + N;
    int*   seg   = (int*)(a_dst + N);    // N+1 ints

    prep<<<dim3((N * 16 + 255) / 256), dim3(256), 0, stream>>>(h, w, a_src, a_dst, N);
    seg_edges<<<dim3((E + 255) / 256), dim3(256), 0, stream>>>(dst, seg, N, E);
    gat_out<<<dim3((N + 3) / 4), dim3(256), 0, stream>>>(h, a_src, a_dst, src, seg, out, N);
}

// Round 5
// 42.755 us; speedup vs baseline: 1.9617x; 1.0684x over previous
//
#include <hip/hip_runtime.h>
#include <math.h>

#define NEG_SLOPE 0.01f

// Fused prep: blocks [0,PB) compute per-node dot products (16 lanes/node, float4);
// blocks [PB,...) compute segment boundaries edge-parallel over sorted dst.
__global__ void prep2(const float* __restrict__ h, const float* __restrict__ w,
                      const int* __restrict__ dst,
                      float* __restrict__ a_src, float* __restrict__ a_dst,
                      int* __restrict__ seg, int N, int E, int PB) {
    if ((int)blockIdx.x < PB) {
        int gid  = blockIdx.x * blockDim.x + threadIdx.x;
        int node = gid >> 4, q = gid & 15;
        if (node >= N) return;
        float4 hv = *(const float4*)(h + (long)node * 64 + q * 4);
        float4 ws = *(const float4*)(w + q * 4);
        float4 wd = *(const float4*)(w + 64 + q * 4);
        float ps = hv.x * ws.x + hv.y * ws.y + hv.z * ws.z + hv.w * ws.w;
        float pd = hv.x * wd.x + hv.y * wd.y + hv.z * wd.z + hv.w * wd.w;
        #pragma unroll
        for (int o = 8; o; o >>= 1) { ps += __shfl_xor(ps, o); pd += __shfl_xor(pd, o); }
        if (q == 0) { a_src[node] = ps; a_dst[node] = pd; }
    } else {
        int i = (blockIdx.x - PB) * blockDim.x + threadIdx.x;
        if (i >= E) return;
        int d    = dst[i];
        int prev = (i == 0) ? -1 : dst[i - 1];
        for (int n = prev + 1; n <= d; ++n) seg[n] = i;
        if (i == E - 1) {
            for (int n = d + 1; n <= N; ++n) seg[n] = E;
        }
    }
}

// gat_out: 16 lanes per node, 4 nodes per wave.
// Softmax per 16-lane group (chunks of 16 edges, deg<=64 fast path).
// Accumulate: group iterates its edges; lane q loads float4 features [q*4..q*4+3]
// of edge j's src row (256B coalesced per group). Iterations padded to wave-max
// degree with alpha=0 so all 64 lanes stay active through every shfl.
__global__ void gat_out(const float* __restrict__ h, const float* __restrict__ a_src,
                        const float* __restrict__ a_dst, const int* __restrict__ src,
                        const int* __restrict__ seg, float* __restrict__ out, int N) {
    int gid   = blockIdx.x * blockDim.x + threadIdx.x;
    int node  = gid >> 4;
    if (node >= N) return;
    int lane  = threadIdx.x & 63;
    int q     = lane & 15;
    int gbase = lane & 48;                 // group base lane (g*16)
    int s     = seg[node];
    int eend  = seg[node + 1];
    int deg   = eend - s;                  // >= 0
    float* orow = out + (long)node * 64 + q * 4;

    // wave-max degree (all 64 lanes active here)
    int wdeg = deg;
    wdeg = max(wdeg, __shfl_xor(wdeg, 16));
    wdeg = max(wdeg, __shfl_xor(wdeg, 32));

    float ad = a_dst[node];
    float4 acc = {0.0f, 0.0f, 0.0f, 0.0f};
    const float* hq = h + q * 4;

    if (wdeg <= 64) {                      // wave-uniform branch
        int   sj0 = 0, sj1 = 0, sj2 = 0, sj3 = 0;
        float e0 = -INFINITY, e1 = -INFINITY, e2 = -INFINITY, e3 = -INFINITY;
        if (q < deg)      { sj0 = src[s + q];      float t = a_src[sj0] + ad; e0 = (t >= 0.f) ? t : NEG_SLOPE * t; }
        if (q + 16 < deg) { sj1 = src[s + q + 16]; float t = a_src[sj1] + ad; e1 = (t >= 0.f) ? t : NEG_SLOPE * t; }
        if (q + 32 < deg) { sj2 = src[s + q + 32]; float t = a_src[sj2] + ad; e2 = (t >= 0.f) ? t : NEG_SLOPE * t; }
        if (q + 48 < deg) { sj3 = src[s + q + 48]; float t = a_src[sj3] + ad; e3 = (t >= 0.f) ? t : NEG_SLOPE * t; }
        float m = fmaxf(fmaxf(e0, e1), fmaxf(e2, e3));
        #pragma unroll
        for (int o = 8; o; o >>= 1) m = fmaxf(m, __shfl_xor(m, o));
        float p0 = (q < deg)      ? __expf(e0 - m) : 0.0f;
        float p1 = (q + 16 < deg) ? __expf(e1 - m) : 0.0f;
        float p2 = (q + 32 < deg) ? __expf(e2 - m) : 0.0f;
        float p3 = (q + 48 < deg) ? __expf(e3 - m) : 0.0f;
        float dsum = p0 + p1 + p2 + p3;
        #pragma unroll
        for (int o = 8; o; o >>= 1) dsum += __shfl_xor(dsum, o);
        float inv = (dsum > 0.0f) ? (1.0f / dsum) : 0.0f;   // deg==0 -> alphas 0
        p0 *= inv; p1 *= inv; p2 *= inv; p3 *= inv;

        // Accumulate. All lanes run to wave-max chunk counts; padding lanes have
        // p=0 (fmaf no-op) and sj=0 (harmless cached row-0 load).
        #define CHUNK(P, SJ, BASE)                                              \
        {   int cnt = wdeg - (BASE); cnt = (cnt > 16) ? 16 : cnt;               \
            _Pragma("unroll 8")                                                 \
            for (int j = 0; j < cnt; ++j) {                                     \
                float aj  = __shfl((P), gbase + j);                             \
                int   sjj = __shfl((SJ), gbase + j);                            \
                float4 hv = *(const float4*)(hq + (long)sjj * 64);              \
                acc.x = fmaf(aj, hv.x, acc.x); acc.y = fmaf(aj, hv.y, acc.y);   \
                acc.z = fmaf(aj, hv.z, acc.z); acc.w = fmaf(aj, hv.w, acc.w);   \
            }                                                                   \
        }
        CHUNK(p0, sj0, 0)
        if (wdeg > 16) CHUNK(p1, sj1, 16)
        if (wdeg > 32) CHUNK(p2, sj2, 32)
        if (wdeg > 48) CHUNK(p3, sj3, 48)
        #undef CHUNK
        *(float4*)orow = acc;
    } else {
        // Rare generic path (some group in wave has deg>64): 16-lane strided
        // 3-pass softmax + serial deterministic accumulation.
        float m = -INFINITY;
        for (int i = s + q; i < eend; i += 16) {
            float t = a_src[src[i]] + ad;
            t = (t >= 0.f) ? t : NEG_SLOPE * t;
            m = fmaxf(m, t);
        }
        #pragma unroll
        for (int o = 8; o; o >>= 1) m = fmaxf(m, __shfl_xor(m, o));
        float dsum = 0.0f;
        for (int i = s + q; i < eend; i += 16) {
            float t = a_src[src[i]] + ad;
            t = (t >= 0.f) ? t : NEG_SLOPE * t;
            dsum += __expf(t - m);
        }
        #pragma unroll
        for (int o = 8; o; o >>= 1) dsum += __shfl_xor(dsum, o);
        float inv = (dsum > 0.0f) ? (1.0f / dsum) : 0.0f;
        for (int i = s; i < eend; ++i) {
            int   sj = src[i];                       // group-broadcast load
            float t  = a_src[sj] + ad;
            t = (t >= 0.f) ? t : NEG_SLOPE * t;
            float aj = __expf(t - m) * inv;
            float4 hv = *(const float4*)(hq + (long)sj * 64);
            acc.x = fmaf(aj, hv.x, acc.x); acc.y = fmaf(aj, hv.y, acc.y);
            acc.z = fmaf(aj, hv.z, acc.z); acc.w = fmaf(aj, hv.w, acc.w);
        }
        *(float4*)orow = acc;
    }
}

extern "C" void kernel_launch(void* const* d_in, const int* in_sizes, int n_in,
                              void* d_out, int out_size, void* d_ws, size_t ws_size,
                              hipStream_t stream) {
    const float* h   = (const float*)d_in[0];
    const float* w   = (const float*)d_in[1];
    const int*   src = (const int*)d_in[2];
    const int*   dst = (const int*)d_in[3];
    float*       out = (float*)d_out;

    const int F = in_sizes[1] / 2;       // 64
    const int N = in_sizes[0] / F;       // 50000
    const int E = in_sizes[2];           // 800000

    float* a_src = (float*)d_ws;
    float* a_dst = a_src + N;
    int*   seg   = (int*)(a_dst + N);    // N+1 ints

    const int PB = (N * 16 + 255) / 256;          // prep blocks
    const int SB = (E + 255) / 256;               // seg blocks
    prep2<<<dim3(PB + SB), dim3(256), 0, stream>>>(h, w, dst, a_src, a_dst, seg, N, E, PB);
    gat_out<<<dim3((N * 16 + 255) / 256), dim3(256), 0, stream>>>(h, a_src, a_dst, src, seg, out, N);
}

// Round 6
// 40.166 us; speedup vs baseline: 2.0881x; 1.0644x over previous
//
#include <hip/hip_runtime.h>
#include <math.h>

#define NEG_SLOPE 0.01f

__device__ __forceinline__ unsigned short f2bf_rne(float f) {
    unsigned int u = __float_as_uint(f);
    u += 0x7fffu + ((u >> 16) & 1u);          // round-to-nearest-even
    return (unsigned short)(u >> 16);
}
__device__ __forceinline__ float bf2f(unsigned short b) {
    return __uint_as_float((unsigned int)b << 16);
}

// Fused prep: blocks [0,PB): per-node dot products (16 lanes/node, float4) AND
// write a bf16 copy of h (hb) for the gather kernel. Blocks [PB,...): edge-parallel
// segment boundaries over sorted dst.
__global__ void prep2(const float* __restrict__ h, const float* __restrict__ w,
                      const int* __restrict__ dst,
                      float* __restrict__ a_src, float* __restrict__ a_dst,
                      int* __restrict__ seg, ushort4* __restrict__ hb,
                      int N, int E, int PB) {
    if ((int)blockIdx.x < PB) {
        int gid  = blockIdx.x * blockDim.x + threadIdx.x;
        int node = gid >> 4, q = gid & 15;
        if (node >= N) return;
        float4 hv = *(const float4*)(h + (long)node * 64 + q * 4);
        float4 ws = *(const float4*)(w + q * 4);
        float4 wd = *(const float4*)(w + 64 + q * 4);
        // bf16 copy (row-major [N][64], lane writes 8B)
        ushort4 hb4 = { f2bf_rne(hv.x), f2bf_rne(hv.y), f2bf_rne(hv.z), f2bf_rne(hv.w) };
        hb[(long)node * 16 + q] = hb4;
        float ps = hv.x * ws.x + hv.y * ws.y + hv.z * ws.z + hv.w * ws.w;
        float pd = hv.x * wd.x + hv.y * wd.y + hv.z * wd.z + hv.w * wd.w;
        #pragma unroll
        for (int o = 8; o; o >>= 1) { ps += __shfl_xor(ps, o); pd += __shfl_xor(pd, o); }
        if (q == 0) { a_src[node] = ps; a_dst[node] = pd; }
    } else {
        int i = (blockIdx.x - PB) * blockDim.x + threadIdx.x;
        if (i >= E) return;
        int d    = dst[i];
        int prev = (i == 0) ? -1 : dst[i - 1];
        for (int n = prev + 1; n <= d; ++n) seg[n] = i;
        if (i == E - 1) {
            for (int n = d + 1; n <= N; ++n) seg[n] = E;
        }
    }
}

// gat_out: 16 lanes per node, 4 nodes per wave. Softmax per 16-lane group in fp32
// (alpha exact); feature gather from bf16 hb rows (8B/lane, 128B/row per group).
__global__ void gat_out(const ushort4* __restrict__ hb, const float* __restrict__ a_src,
                        const float* __restrict__ a_dst, const int* __restrict__ src,
                        const int* __restrict__ seg, float* __restrict__ out, int N) {
    int gid   = blockIdx.x * blockDim.x + threadIdx.x;
    int node  = gid >> 4;
    if (node >= N) return;
    int lane  = threadIdx.x & 63;
    int q     = lane & 15;
    int gbase = lane & 48;                 // group base lane (g*16)
    int s     = seg[node];
    int eend  = seg[node + 1];
    int deg   = eend - s;                  // >= 0
    float* orow = out + (long)node * 64 + q * 4;

    // wave-max degree (wave-uniform branch selector)
    int wdeg = deg;
    wdeg = max(wdeg, __shfl_xor(wdeg, 16));
    wdeg = max(wdeg, __shfl_xor(wdeg, 32));

    float ad = a_dst[node];
    float4 acc = {0.0f, 0.0f, 0.0f, 0.0f};
    const ushort4* hq = hb + q;

    if (wdeg <= 64) {
        int   sj0 = 0, sj1 = 0, sj2 = 0, sj3 = 0;
        float e0 = -INFINITY, e1 = -INFINITY, e2 = -INFINITY, e3 = -INFINITY;
        if (q < deg)      { sj0 = src[s + q];      float t = a_src[sj0] + ad; e0 = (t >= 0.f) ? t : NEG_SLOPE * t; }
        if (q + 16 < deg) { sj1 = src[s + q + 16]; float t = a_src[sj1] + ad; e1 = (t >= 0.f) ? t : NEG_SLOPE * t; }
        if (q + 32 < deg) { sj2 = src[s + q + 32]; float t = a_src[sj2] + ad; e2 = (t >= 0.f) ? t : NEG_SLOPE * t; }
        if (q + 48 < deg) { sj3 = src[s + q + 48]; float t = a_src[sj3] + ad; e3 = (t >= 0.f) ? t : NEG_SLOPE * t; }
        float m = fmaxf(fmaxf(e0, e1), fmaxf(e2, e3));
        #pragma unroll
        for (int o = 8; o; o >>= 1) m = fmaxf(m, __shfl_xor(m, o));
        float p0 = (q < deg)      ? __expf(e0 - m) : 0.0f;
        float p1 = (q + 16 < deg) ? __expf(e1 - m) : 0.0f;
        float p2 = (q + 32 < deg) ? __expf(e2 - m) : 0.0f;
        float p3 = (q + 48 < deg) ? __expf(e3 - m) : 0.0f;
        float dsum = p0 + p1 + p2 + p3;
        #pragma unroll
        for (int o = 8; o; o >>= 1) dsum += __shfl_xor(dsum, o);
        float inv = (dsum > 0.0f) ? (1.0f / dsum) : 0.0f;
        p0 *= inv; p1 *= inv; p2 *= inv; p3 *= inv;

        // Padding lanes have p=0 (fmaf no-op) and sj=0 (harmless cached load).
        #define CHUNK(P, SJ, BASE)                                              \
        {   int cnt = wdeg - (BASE); cnt = (cnt > 16) ? 16 : cnt;               \
            _Pragma("unroll 8")                                                 \
            for (int j = 0; j < cnt; ++j) {                                     \
                float aj  = __shfl((P), gbase + j);                             \
                int   sjj = __shfl((SJ), gbase + j);                            \
                ushort4 hv = hq[(long)sjj * 16];                                \
                acc.x = fmaf(aj, bf2f(hv.x), acc.x);                            \
                acc.y = fmaf(aj, bf2f(hv.y), acc.y);                            \
                acc.z = fmaf(aj, bf2f(hv.z), acc.z);                            \
                acc.w = fmaf(aj, bf2f(hv.w), acc.w);                            \
            }                                                                   \
        }
        CHUNK(p0, sj0, 0)
        if (wdeg > 16) CHUNK(p1, sj1, 16)
        if (wdeg > 32) CHUNK(p2, sj2, 32)
        if (wdeg > 48) CHUNK(p3, sj3, 48)
        #undef CHUNK
        *(float4*)orow = acc;
    } else {
        // Rare generic path (some group has deg>64): 16-lane strided 3-pass
        // softmax + serial deterministic accumulation.
        float m = -INFINITY;
        for (int i = s + q; i < eend; i += 16) {
            float t = a_src[src[i]] + ad;
            t = (t >= 0.f) ? t : NEG_SLOPE * t;
            m = fmaxf(m, t);
        }
        #pragma unroll
        for (int o = 8; o; o >>= 1) m = fmaxf(m, __shfl_xor(m, o));
        float dsum = 0.0f;
        for (int i = s + q; i < eend; i += 16) {
            float t = a_src[src[i]] + ad;
            t = (t >= 0.f) ? t : NEG_SLOPE * t;
            dsum += __expf(t - m);
        }
        #pragma unroll
        for (int o = 8; o; o >>= 1) dsum += __shfl_xor(dsum, o);
        float inv = (dsum > 0.0f) ? (1.0f / dsum) : 0.0f;
        for (int i = s; i < eend; ++i) {
            int   sj = src[i];
            float t  = a_src[sj] + ad;
            t = (t >= 0.f) ? t : NEG_SLOPE * t;
            float aj = __expf(t - m) * inv;
            ushort4 hv = hq[(long)sj * 16];
            acc.x = fmaf(aj, bf2f(hv.x), acc.x);
            acc.y = fmaf(aj, bf2f(hv.y), acc.y);
            acc.z = fmaf(aj, bf2f(hv.z), acc.z);
            acc.w = fmaf(aj, bf2f(hv.w), acc.w);
        }
        *(float4*)orow = acc;
    }
}

extern "C" void kernel_launch(void* const* d_in, const int* in_sizes, int n_in,
                              void* d_out, int out_size, void* d_ws, size_t ws_size,
                              hipStream_t stream) {
    const float* h   = (const float*)d_in[0];
    const float* w   = (const float*)d_in[1];
    const int*   src = (const int*)d_in[2];
    const int*   dst = (const int*)d_in[3];
    float*       out = (float*)d_out;

    const int F = in_sizes[1] / 2;       // 64
    const int N = in_sizes[0] / F;       // 50000
    const int E = in_sizes[2];           // 800000

    char* wsb   = (char*)d_ws;
    float* a_src = (float*)wsb;                          // N floats
    float* a_dst = a_src + N;                            // N floats
    int*   seg   = (int*)(a_dst + N);                    // N+1 ints
    size_t off   = ((size_t)(3 * N + 1) * 4 + 255) & ~(size_t)255;
    ushort4* hb  = (ushort4*)(wsb + off);                // N*64 bf16 = N*16 ushort4

    const int PB = (N * 16 + 255) / 256;          // prep blocks
    const int SB = (E + 255) / 256;               // seg blocks
    prep2<<<dim3(PB + SB), dim3(256), 0, stream>>>(h, w, dst, a_src, a_dst, seg, hb, N, E, PB);
    gat_out<<<dim3((N * 16 + 255) / 256), dim3(256), 0, stream>>>(hb, a_src, a_dst, src, seg, out, N);
}

// Round 7
// 35.738 us; speedup vs baseline: 2.3469x; 1.1239x over previous
//
#include <hip/hip_runtime.h>
#include <math.h>

#define NEG_SLOPE 0.01f

__device__ __forceinline__ unsigned short f2bf_rne(float f) {
    unsigned int u = __float_as_uint(f);
    u += 0x7fffu + ((u >> 16) & 1u);          // round-to-nearest-even
    return (unsigned short)(u >> 16);
}
__device__ __forceinline__ float bf2f(unsigned short b) {
    return __uint_as_float((unsigned int)b << 16);
}

// K1: per-node dot products (16 lanes/node, float4) + bf16 copy of h.
__global__ void prep(const float* __restrict__ h, const float* __restrict__ w,
                     float* __restrict__ a_src, float* __restrict__ a_dst,
                     ushort4* __restrict__ hb, int N) {
    int gid  = blockIdx.x * blockDim.x + threadIdx.x;
    int node = gid >> 4, q = gid & 15;
    if (node >= N) return;
    float4 hv = *(const float4*)(h + (long)node * 64 + q * 4);
    float4 ws = *(const float4*)(w + q * 4);
    float4 wd = *(const float4*)(w + 64 + q * 4);
    ushort4 hb4 = { f2bf_rne(hv.x), f2bf_rne(hv.y), f2bf_rne(hv.z), f2bf_rne(hv.w) };
    hb[(long)node * 16 + q] = hb4;
    float ps = hv.x * ws.x + hv.y * ws.y + hv.z * ws.z + hv.w * ws.w;
    float pd = hv.x * wd.x + hv.y * wd.y + hv.z * wd.z + hv.w * wd.w;
    #pragma unroll
    for (int o = 8; o; o >>= 1) { ps += __shfl_xor(ps, o); pd += __shfl_xor(pd, o); }
    if (q == 0) { a_src[node] = ps; a_dst[node] = pd; }
}

// K2: edge-parallel. e[i] = leaky(a_src[src[i]] + a_dst[dst[i]]) (the scatter,
// hidden by pure MLP: 4 independent gathers/thread, nothing dependent after).
// Also fills seg[] boundaries from sorted dst.
__global__ void edge_e(const int* __restrict__ src, const int* __restrict__ dst,
                       const float* __restrict__ a_src, const float* __restrict__ a_dst,
                       float* __restrict__ e, int* __restrict__ seg, int N, int E) {
    int i0 = (blockIdx.x * blockDim.x + threadIdx.x) * 4;
    if (i0 >= E) return;
    if (i0 + 4 <= E) {
        int4 s4 = *(const int4*)(src + i0);
        int4 d4 = *(const int4*)(dst + i0);
        int prev = (i0 == 0) ? -1 : dst[i0 - 1];
        float4 ev; float t;
        t = a_src[s4.x] + a_dst[d4.x]; ev.x = (t >= 0.f) ? t : NEG_SLOPE * t;
        t = a_src[s4.y] + a_dst[d4.y]; ev.y = (t >= 0.f) ? t : NEG_SLOPE * t;
        t = a_src[s4.z] + a_dst[d4.z]; ev.z = (t >= 0.f) ? t : NEG_SLOPE * t;
        t = a_src[s4.w] + a_dst[d4.w]; ev.w = (t >= 0.f) ? t : NEG_SLOPE * t;
        *(float4*)(e + i0) = ev;
        for (int n = prev + 1; n <= d4.x; ++n) seg[n] = i0;
        for (int n = d4.x + 1; n <= d4.y; ++n) seg[n] = i0 + 1;
        for (int n = d4.y + 1; n <= d4.z; ++n) seg[n] = i0 + 2;
        for (int n = d4.z + 1; n <= d4.w; ++n) seg[n] = i0 + 3;
        if (i0 + 4 == E) { for (int n = d4.w + 1; n <= N; ++n) seg[n] = E; }
    } else {
        for (int i = i0; i < E; ++i) {
            int sj = src[i], dj = dst[i];
            int prev = (i == 0) ? -1 : dst[i - 1];
            float t = a_src[sj] + a_dst[dj];
            e[i] = (t >= 0.f) ? t : NEG_SLOPE * t;
            for (int n = prev + 1; n <= dj; ++n) seg[n] = i;
            if (i == E - 1) { for (int n = dj + 1; n <= N; ++n) seg[n] = E; }
        }
    }
}

// K3: 16 lanes/node, 4 nodes/wave. Softmax head reads contiguous e[] (no scatter).
// (alpha, sj) pairs staged in bank-padded LDS (group-uniform broadcast reads);
// accumulate in statically-indexed chunks of 8: 8 pair reads -> 8 independent
// bf16 row loads in flight -> 8 fmas. Padded slots have alpha=0, sj=0.
__global__ void gat_out(const ushort4* __restrict__ hb, const float* __restrict__ e,
                        const int* __restrict__ src, const int* __restrict__ seg,
                        float* __restrict__ out, int N) {
    int gid  = blockIdx.x * blockDim.x + threadIdx.x;
    int node = gid >> 4;
    if (node >= N) return;
    int tid  = threadIdx.x;
    int lane = tid & 63, q = lane & 15, g = (lane >> 4) & 3, wv = tid >> 6;
    int s    = seg[node];
    int eend = seg[node + 1];
    int deg  = eend - s;
    float* orow = out + (long)node * 64 + q * 4;

    __shared__ float2 pair[4][4][66];     // [wave][group][slot], padded stride: no bank conflicts

    int wdeg = deg;
    wdeg = max(wdeg, __shfl_xor(wdeg, 16));
    wdeg = max(wdeg, __shfl_xor(wdeg, 32));

    const ushort4* hq = hb + q;
    float4 acc = {0.0f, 0.0f, 0.0f, 0.0f};

    if (wdeg <= 64) {
        float e0 = -INFINITY, e1 = -INFINITY, e2 = -INFINITY, e3 = -INFINITY;
        int   sj0 = 0, sj1 = 0, sj2 = 0, sj3 = 0;
        if (q < deg)      { e0 = e[s + q];      sj0 = src[s + q]; }
        if (q + 16 < deg) { e1 = e[s + q + 16]; sj1 = src[s + q + 16]; }
        if (q + 32 < deg) { e2 = e[s + q + 32]; sj2 = src[s + q + 32]; }
        if (q + 48 < deg) { e3 = e[s + q + 48]; sj3 = src[s + q + 48]; }
        float m = fmaxf(fmaxf(e0, e1), fmaxf(e2, e3));
        #pragma unroll
        for (int o = 8; o; o >>= 1) m = fmaxf(m, __shfl_xor(m, o));
        float p0 = (q < deg)      ? __expf(e0 - m) : 0.0f;
        float p1 = (q + 16 < deg) ? __expf(e1 - m) : 0.0f;
        float p2 = (q + 32 < deg) ? __expf(e2 - m) : 0.0f;
        float p3 = (q + 48 < deg) ? __expf(e3 - m) : 0.0f;
        float dsum = p0 + p1 + p2 + p3;
        #pragma unroll
        for (int o = 8; o; o >>= 1) dsum += __shfl_xor(dsum, o);
        float inv = (dsum > 0.0f) ? (1.0f / dsum) : 0.0f;

        float2* gp = pair[wv][g];
        gp[q]      = make_float2(p0 * inv, __int_as_float(sj0));
        gp[q + 16] = make_float2(p1 * inv, __int_as_float(sj1));
        gp[q + 32] = make_float2(p2 * inv, __int_as_float(sj2));
        gp[q + 48] = make_float2(p3 * inv, __int_as_float(sj3));
        // same-wave produce->consume; compiler inserts lgkmcnt ordering

        int dr = (deg + 7) & ~7;          // padded slots carry alpha=0
        for (int j0 = 0; j0 < dr; j0 += 8) {
            float a_[8]; int s_[8];
            #pragma unroll
            for (int k = 0; k < 8; ++k) {
                float2 pr = gp[j0 + k];   // group-uniform LDS broadcast
                a_[k] = pr.x; s_[k] = __float_as_int(pr.y);
            }
            ushort4 r_[8];
            #pragma unroll
            for (int k = 0; k < 8; ++k) r_[k] = hq[(long)s_[k] * 16];  // 8 loads in flight
            #pragma unroll
            for (int k = 0; k < 8; ++k) {
                acc.x = fmaf(a_[k], bf2f(r_[k].x), acc.x);
                acc.y = fmaf(a_[k], bf2f(r_[k].y), acc.y);
                acc.z = fmaf(a_[k], bf2f(r_[k].z), acc.z);
                acc.w = fmaf(a_[k], bf2f(r_[k].w), acc.w);
            }
        }
        *(float4*)orow = acc;
    } else {
        // Rare fallback (some group has deg>64): strided 3-pass on e[], serial accumulate.
        float m = -INFINITY;
        for (int i = s + q; i < eend; i += 16) m = fmaxf(m, e[i]);
        #pragma unroll
        for (int o = 8; o; o >>= 1) m = fmaxf(m, __shfl_xor(m, o));
        float dsum = 0.0f;
        for (int i = s + q; i < eend; i += 16) dsum += __expf(e[i] - m);
        #pragma unroll
        for (int o = 8; o; o >>= 1) dsum += __shfl_xor(dsum, o);
        float inv = (dsum > 0.0f) ? (1.0f / dsum) : 0.0f;
        for (int i = s; i < eend; ++i) {
            float aj = __expf(e[i] - m) * inv;       // uniform loads within group
            int   sj = src[i];
            ushort4 hv = hq[(long)sj * 16];
            acc.x = fmaf(aj, bf2f(hv.x), acc.x);
            acc.y = fmaf(aj, bf2f(hv.y), acc.y);
            acc.z = fmaf(aj, bf2f(hv.z), acc.z);
            acc.w = fmaf(aj, bf2f(hv.w), acc.w);
        }
        *(float4*)orow = acc;
    }
}

extern "C" void kernel_launch(void* const* d_in, const int* in_sizes, int n_in,
                              void* d_out, int out_size, void* d_ws, size_t ws_size,
                              hipStream_t stream) {
    const float* h   = (const float*)d_in[0];
    const float* w   = (const float*)d_in[1];
    const int*   src = (const int*)d_in[2];
    const int*   dst = (const int*)d_in[3];
    float*       out = (float*)d_out;

    const int F = in_sizes[1] / 2;       // 64
    const int N = in_sizes[0] / F;       // 50000
    const int E = in_sizes[2];           // 800000

    char*  wsb   = (char*)d_ws;
    float* a_src = (float*)wsb;                          // N floats
    float* a_dst = a_src + N;                            // N floats
    int*   seg   = (int*)(a_dst + N);                    // N+1 ints
    float* ebuf  = (float*)(seg + N + 1);                // E floats
    size_t off   = (((size_t)(3 * N + 1) + E) * 4 + 255) & ~(size_t)255;
    ushort4* hb  = (ushort4*)(wsb + off);                // N*64 bf16

    prep   <<<dim3((N * 16 + 255) / 256), dim3(256), 0, stream>>>(h, w, a_src, a_dst, hb, N);
    edge_e <<<dim3((E / 4 + 255) / 256), dim3(256), 0, stream>>>(src, dst, a_src, a_dst, ebuf, seg, N, E);
    gat_out<<<dim3((N * 16 + 255) / 256), dim3(256), 0, stream>>>(hb, ebuf, src, seg, out, N);
}

// Round 8
// 35.658 us; speedup vs baseline: 2.3521x; 1.0022x over previous
//
#include <hip/hip_runtime.h>
#include <math.h>

#define NEG_SLOPE 0.01f

__device__ __forceinline__ unsigned short f2bf_rne(float f) {
    unsigned int u = __float_as_uint(f);
    u += 0x7fffu + ((u >> 16) & 1u);          // round-to-nearest-even
    return (unsigned short)(u >> 16);
}
__device__ __forceinline__ float bf2f(unsigned short b) {
    return __uint_as_float((unsigned int)b << 16);
}

// K1: per-node dot products (16 lanes/node, float4) + bf16 copy of h.
__global__ void prep(const float* __restrict__ h, const float* __restrict__ w,
                     float* __restrict__ a_src, float* __restrict__ a_dst,
                     ushort4* __restrict__ hb, int N) {
    int gid  = blockIdx.x * blockDim.x + threadIdx.x;
    int node = gid >> 4, q = gid & 15;
    if (node >= N) return;
    float4 hv = *(const float4*)(h + (long)node * 64 + q * 4);
    float4 ws = *(const float4*)(w + q * 4);
    float4 wd = *(const float4*)(w + 64 + q * 4);
    ushort4 hb4 = { f2bf_rne(hv.x), f2bf_rne(hv.y), f2bf_rne(hv.z), f2bf_rne(hv.w) };
    hb[(long)node * 16 + q] = hb4;
    float ps = hv.x * ws.x + hv.y * ws.y + hv.z * ws.z + hv.w * ws.w;
    float pd = hv.x * wd.x + hv.y * wd.y + hv.z * wd.z + hv.w * wd.w;
    #pragma unroll
    for (int o = 8; o; o >>= 1) { ps += __shfl_xor(ps, o); pd += __shfl_xor(pd, o); }
    if (q == 0) { a_src[node] = ps; a_dst[node] = pd; }
}

// K2: edge-parallel e[i] = leaky(a_src[src[i]] + a_dst[dst[i]]) + seg boundaries.
__global__ void edge_e(const int* __restrict__ src, const int* __restrict__ dst,
                       const float* __restrict__ a_src, const float* __restrict__ a_dst,
                       float* __restrict__ e, int* __restrict__ seg, int N, int E) {
    int i0 = (blockIdx.x * blockDim.x + threadIdx.x) * 4;
    if (i0 >= E) return;
    if (i0 + 4 <= E) {
        int4 s4 = *(const int4*)(src + i0);
        int4 d4 = *(const int4*)(dst + i0);
        int prev = (i0 == 0) ? -1 : dst[i0 - 1];
        float4 ev; float t;
        t = a_src[s4.x] + a_dst[d4.x]; ev.x = (t >= 0.f) ? t : NEG_SLOPE * t;
        t = a_src[s4.y] + a_dst[d4.y]; ev.y = (t >= 0.f) ? t : NEG_SLOPE * t;
        t = a_src[s4.z] + a_dst[d4.z]; ev.z = (t >= 0.f) ? t : NEG_SLOPE * t;
        t = a_src[s4.w] + a_dst[d4.w]; ev.w = (t >= 0.f) ? t : NEG_SLOPE * t;
        *(float4*)(e + i0) = ev;
        for (int n = prev + 1; n <= d4.x; ++n) seg[n] = i0;
        for (int n = d4.x + 1; n <= d4.y; ++n) seg[n] = i0 + 1;
        for (int n = d4.y + 1; n <= d4.z; ++n) seg[n] = i0 + 2;
        for (int n = d4.z + 1; n <= d4.w; ++n) seg[n] = i0 + 3;
        if (i0 + 4 == E) { for (int n = d4.w + 1; n <= N; ++n) seg[n] = E; }
    } else {
        for (int i = i0; i < E; ++i) {
            int sj = src[i], dj = dst[i];
            int prev = (i == 0) ? -1 : dst[i - 1];
            float t = a_src[sj] + a_dst[dj];
            e[i] = (t >= 0.f) ? t : NEG_SLOPE * t;
            for (int n = prev + 1; n <= dj; ++n) seg[n] = i;
            if (i == E - 1) { for (int n = dj + 1; n <= N; ++n) seg[n] = E; }
        }
    }
}

// K3: 16 lanes/node, 4 nodes/wave.
// NEW: chunk-0's 8 row gathers are issued BEFORE the softmax reduce (row ids
// depend only on sj) — the shfl trees / exp / LDS write execute under the
// in-flight loads. Chunk-0 alphas come via shfl of p0*inv; chunks >=1 use the
// LDS (alpha,sj) pair path.
__global__ void gat_out(const ushort4* __restrict__ hb, const float* __restrict__ e,
                        const int* __restrict__ src, const int* __restrict__ seg,
                        float* __restrict__ out, int N) {
    int gid  = blockIdx.x * blockDim.x + threadIdx.x;
    int node = gid >> 4;
    if (node >= N) return;
    int tid  = threadIdx.x;
    int lane = tid & 63, q = lane & 15, g = (lane >> 4) & 3, wv = tid >> 6;
    int s    = seg[node];
    int eend = seg[node + 1];
    int deg  = eend - s;
    float* orow = out + (long)node * 64 + q * 4;

    __shared__ float2 pair[4][4][66];     // [wave][group][slot], padded: no bank conflicts

    int wdeg = deg;
    wdeg = max(wdeg, __shfl_xor(wdeg, 16));
    wdeg = max(wdeg, __shfl_xor(wdeg, 32));

    const ushort4* hq = hb + q;
    int gbase = lane & 48;
    float4 acc = {0.0f, 0.0f, 0.0f, 0.0f};

    if (wdeg <= 64) {
        float e0 = -INFINITY, e1 = -INFINITY, e2 = -INFINITY, e3 = -INFINITY;
        int   sj0 = 0, sj1 = 0, sj2 = 0, sj3 = 0;
        if (q < deg)      { e0 = e[s + q];      sj0 = src[s + q]; }
        if (q + 16 < deg) { e1 = e[s + q + 16]; sj1 = src[s + q + 16]; }
        if (q + 32 < deg) { e2 = e[s + q + 32]; sj2 = src[s + q + 32]; }
        if (q + 48 < deg) { e3 = e[s + q + 48]; sj3 = src[s + q + 48]; }

        // ---- chunk-0 prefetch: row ids for edges 0..7, loads issued now ----
        int s0_[8];
        #pragma unroll
        for (int k = 0; k < 8; ++k) s0_[k] = __shfl(sj0, gbase + k);
        ushort4 r0_[8];
        #pragma unroll
        for (int k = 0; k < 8; ++k) r0_[k] = hq[(long)s0_[k] * 16];

        // ---- softmax executes while chunk-0 gathers are in flight ----
        float m = fmaxf(fmaxf(e0, e1), fmaxf(e2, e3));
        #pragma unroll
        for (int o = 8; o; o >>= 1) m = fmaxf(m, __shfl_xor(m, o));
        float p0 = (q < deg)      ? __expf(e0 - m) : 0.0f;
        float p1 = (q + 16 < deg) ? __expf(e1 - m) : 0.0f;
        float p2 = (q + 32 < deg) ? __expf(e2 - m) : 0.0f;
        float p3 = (q + 48 < deg) ? __expf(e3 - m) : 0.0f;
        float dsum = p0 + p1 + p2 + p3;
        #pragma unroll
        for (int o = 8; o; o >>= 1) dsum += __shfl_xor(dsum, o);
        float inv = (dsum > 0.0f) ? (1.0f / dsum) : 0.0f;
        float p0v = p0 * inv;

        float2* gp = pair[wv][g];
        gp[q]      = make_float2(p0v,      __int_as_float(sj0));
        gp[q + 16] = make_float2(p1 * inv, __int_as_float(sj1));
        gp[q + 32] = make_float2(p2 * inv, __int_as_float(sj2));
        gp[q + 48] = make_float2(p3 * inv, __int_as_float(sj3));

        // ---- chunk 0: alphas via shfl, rows already (nearly) arrived ----
        #pragma unroll
        for (int k = 0; k < 8; ++k) {
            float aj = __shfl(p0v, gbase + k);
            acc.x = fmaf(aj, bf2f(r0_[k].x), acc.x);
            acc.y = fmaf(aj, bf2f(r0_[k].y), acc.y);
            acc.z = fmaf(aj, bf2f(r0_[k].z), acc.z);
            acc.w = fmaf(aj, bf2f(r0_[k].w), acc.w);
        }

        // ---- chunks 1+ : LDS pair path (padded slots alpha=0, sj=0) ----
        int dr = (deg + 7) & ~7;
        for (int j0 = 8; j0 < dr; j0 += 8) {
            float a_[8]; int s_[8];
            #pragma unroll
            for (int k = 0; k < 8; ++k) {
                float2 pr = gp[j0 + k];
                a_[k] = pr.x; s_[k] = __float_as_int(pr.y);
            }
            ushort4 r_[8];
            #pragma unroll
            for (int k = 0; k < 8; ++k) r_[k] = hq[(long)s_[k] * 16];
            #pragma unroll
            for (int k = 0; k < 8; ++k) {
                acc.x = fmaf(a_[k], bf2f(r_[k].x), acc.x);
                acc.y = fmaf(a_[k], bf2f(r_[k].y), acc.y);
                acc.z = fmaf(a_[k], bf2f(r_[k].z), acc.z);
                acc.w = fmaf(a_[k], bf2f(r_[k].w), acc.w);
            }
        }
        *(float4*)orow = acc;
    } else {
        // Rare fallback (some group has deg>64): strided 3-pass on e[], serial accumulate.
        float m = -INFINITY;
        for (int i = s + q; i < eend; i += 16) m = fmaxf(m, e[i]);
        #pragma unroll
        for (int o = 8; o; o >>= 1) m = fmaxf(m, __shfl_xor(m, o));
        float dsum = 0.0f;
        for (int i = s + q; i < eend; i += 16) dsum += __expf(e[i] - m);
        #pragma unroll
        for (int o = 8; o; o >>= 1) dsum += __shfl_xor(dsum, o);
        float inv = (dsum > 0.0f) ? (1.0f / dsum) : 0.0f;
        for (int i = s; i < eend; ++i) {
            float aj = __expf(e[i] - m) * inv;
            int   sj = src[i];
            ushort4 hv = hq[(long)sj * 16];
            acc.x = fmaf(aj, bf2f(hv.x), acc.x);
            acc.y = fmaf(aj, bf2f(hv.y), acc.y);
            acc.z = fmaf(aj, bf2f(hv.z), acc.z);
            acc.w = fmaf(aj, bf2f(hv.w), acc.w);
        }
        *(float4*)orow = acc;
    }
}

extern "C" void kernel_launch(void* const* d_in, const int* in_sizes, int n_in,
                              void* d_out, int out_size, void* d_ws, size_t ws_size,
                              hipStream_t stream) {
    const float* h   = (const float*)d_in[0];
    const float* w   = (const float*)d_in[1];
    const int*   src = (const int*)d_in[2];
    const int*   dst = (const int*)d_in[3];
    float*       out = (float*)d_out;

    const int F = in_sizes[1] / 2;       // 64
    const int N = in_sizes[0] / F;       // 50000
    const int E = in_sizes[2];           // 800000

    char*  wsb   = (char*)d_ws;
    float* a_src = (float*)wsb;                          // N floats
    float* a_dst = a_src + N;                            // N floats
    int*   seg   = (int*)(a_dst + N);                    // N+1 ints
    float* ebuf  = (float*)(seg + N + 1);                // E floats
    size_t off   = (((size_t)(3 * N + 1) + E) * 4 + 255) & ~(size_t)255;
    ushort4* hb  = (ushort4*)(wsb + off);                // N*64 bf16

    prep   <<<dim3((N * 16 + 255) / 256), dim3(256), 0, stream>>>(h, w, a_src, a_dst, hb, N);
    edge_e <<<dim3((E / 4 + 255) / 256), dim3(256), 0, stream>>>(src, dst, a_src, a_dst, ebuf, seg, N, E);
    gat_out<<<dim3((N * 16 + 255) / 256), dim3(256), 0, stream>>>(hb, ebuf, src, seg, out, N);
}